// Round 5
// baseline (323.030 us; speedup 1.0000x reference)
//
#include <hip/hip_runtime.h>

static constexpr int B_    = 64;
static constexpr int N_    = 2048;
static constexpr int DI_   = 8;
static constexpr int O_    = 32;
static constexpr int P_    = 16;
static constexpr int OP_   = O_ * P_;      // 512
static constexpr int M_    = OP_ * B_;     // 32768 s elements
static constexpr int CHUNK_ = 8;
static constexpr int NBLK_  = N_ / CHUNK_; // 256 n-chunks
static constexpr int WSLICE_ = O_ * P_ * DI_;  // 4096 floats per n

// DPP add helper: v + dpp_mov(v). CTRL compile-time (0xB1 quad_perm[1,0,3,2];
// 0x121/2/4/8 = row_ror 1/2/4/8).
template <int CTRL>
__device__ __forceinline__ float dpp_add(float v) {
  int t = __builtin_amdgcn_update_dpp(0, __float_as_int(v), CTRL, 0xf, 0xf, false);
  return v + __int_as_float(t);
}

__device__ __forceinline__ float rfl(float v) {
  return __int_as_float(__builtin_amdgcn_readfirstlane(__float_as_int(v)));
}

// R5: R4 ran with ONE 512-thr block/CU resident (occupancy 17.6% ~= 8 waves x
// 0.7 metric factor) and 2 counter-draining barriers per nn + per-nn uniform
// global x loads on the critical path -> lockstep stalls (VALUBusy 35%,
// 14k cyc/nn/SIMD vs ~1.5k issue). Fix = independence + fewer syncs:
//  - 256-thr blocks (4 waves), block = b-quarter (16 b), grid 1024 ->
//    4 independent blocks/CU (LDS 36KB/block, 144KB/CU). Lockstep within a
//    block is filled by the other blocks' waves.
//  - W double-buffered (2x16KB): write buf[(nn+1)&1] while reading buf[nn&1],
//    ONE __syncthreads per nn (halves barrier drains).
//  - x staged once to LDS at prologue; per-nn x = 8 broadcast ds_read_b128
//    (~120cy fixed) -> readfirstlane -> SGPR FMA operands. No per-nn global
//    latency before pass1.
//  - v reloaded per-nn in pass2 (L2-hot): persistent pressure = s_r(32) only;
//    peak ~= s_r32+pr32+wr16+v32 transient ~= 120 < 128 cap
//    (__launch_bounds__(256,4)).
// Unchanged verified machinery: (o,ph) lane remap (4x less LDS->RF traffic
// than lane=b), LDS-internal XOR swizzle (phys chunk = g ^ ((g>>4)&7); read
// addr (lane*64+(lane&7)*4)^(8pp+4h)), in-wave DPP softmax, [b][h][lane][4]
// coalesced epilogue.
template <int MODE, bool ATOMIC>
__global__ __launch_bounds__(256, 4)
void fused_pass(const float* __restrict__ x, const float* __restrict__ W,
                const float* __restrict__ v_in, float* __restrict__ s_out,
                float* __restrict__ rw_out) {
  __shared__ __align__(16) float w_lds[2][WSLICE_];   // 32 KB dbuf
  __shared__ __align__(16) float x_lds[16 * 64];      // 4 KB: [b_local][ch*4]
  const int tid  = threadIdx.x;
  const int lane = tid & 63;
  const int wu   = __builtin_amdgcn_readfirstlane(tid >> 6);  // 0..3
  const int o    = lane >> 1;   // 0..31 output capsule
  const int ph   = lane & 1;    // p-half: p = ph*8 + pp
  const int cn   = blockIdx.x >> 2;      // n-chunk 0..255
  const int bq   = blockIdx.x & 3;       // b-quarter
  const int n0   = cn * CHUNK_;
  const int b0_blk = bq * 16;            // block's first b
  const int b0w  = b0_blk + wu * 4;      // wave's first b (wave-uniform)

  // swizzled W chunk key: phys = (tid ^ ((tid>>4)&7)) + k*256 (k*256 keeps
  // bits 0-6, and ((g>>4)&7) is k-invariant). Float offset:
  const int swk = (tid ^ ((tid >> 4) & 7)) * 4;
  // swizzled read base (floats): per-chunk addr = wbase ^ (8pp [+4])
  const int wbase = lane * 64 + (lane & 7) * 4;

  float s_r[4][8];
  #pragma unroll
  for (int bb = 0; bb < 4; ++bb)
    #pragma unroll
    for (int pp = 0; pp < 8; ++pp) s_r[bb][pp] = 0.0f;

  // ---- prologue: stage x (once) and W[n0] (buf 0)
  {
    const int bl = tid >> 4;    // b_local 0..15
    const int ch = tid & 15;    // 16B chunk within b's 64 floats
    const float4 xv = *(const float4*)(
        x + (size_t)(b0_blk + bl) * (N_ * DI_) + n0 * DI_ + ch * 4);
    *(float4*)&x_lds[bl * 64 + ch * 4] = xv;
    #pragma unroll
    for (int k = 0; k < 4; ++k) {
      const float4 wv =
          *(const float4*)(W + (size_t)n0 * WSLICE_ + (tid + k * 256) * 4);
      *(float4*)&w_lds[0][swk + k * 1024] = wv;
    }
  }
  __syncthreads();

  #pragma unroll 1
  for (int nn = 0; nn < CHUNK_; ++nn) {
    const int n = n0 + nn;
    const float* wbuf = w_lds[nn & 1];
    float* wnxt = w_lds[(nn + 1) & 1];

    // prefetch W[n+1] -> regs (linear, coalesced); ds_write after compute.
    float4 wr0, wr1, wr2, wr3;
    if (nn + 1 < CHUNK_) {
      const float* wp = W + (size_t)(n + 1) * WSLICE_ + tid * 4;
      wr0 = *(const float4*)(wp);
      wr1 = *(const float4*)(wp + 1024);
      wr2 = *(const float4*)(wp + 2048);
      wr3 = *(const float4*)(wp + 3072);
    }

    // x from LDS (broadcast b128, ~120cy) -> SGPR via readfirstlane
    float xs[4][8];
    #pragma unroll
    for (int bb = 0; bb < 4; ++bb) {
      const int xb = (wu * 4 + bb) * 64 + nn * 8;
      const float4 xa = *(const float4*)&x_lds[xb];
      const float4 xc = *(const float4*)&x_lds[xb + 4];
      xs[bb][0] = rfl(xa.x); xs[bb][1] = rfl(xa.y);
      xs[bb][2] = rfl(xa.z); xs[bb][3] = rfl(xa.w);
      xs[bb][4] = rfl(xc.x); xs[bb][5] = rfl(xc.y);
      xs[bb][6] = rfl(xc.z); xs[bb][7] = rfl(xc.w);
    }

    // pass 1: predictions (no v live -> low register peak)
    float pr[4][8];
    #pragma unroll
    for (int pp = 0; pp < 8; ++pp) {
      const float4 w0 = *(const float4*)&wbuf[wbase ^ (8 * pp)];
      const float4 w1 = *(const float4*)&wbuf[wbase ^ (8 * pp + 4)];
      #pragma unroll
      for (int bb = 0; bb < 4; ++bb) {
        float pv = w0.x * xs[bb][0];
        pv = __builtin_fmaf(w0.y, xs[bb][1], pv);
        pv = __builtin_fmaf(w0.z, xs[bb][2], pv);
        pv = __builtin_fmaf(w0.w, xs[bb][3], pv);
        pv = __builtin_fmaf(w1.x, xs[bb][4], pv);
        pv = __builtin_fmaf(w1.y, xs[bb][5], pv);
        pv = __builtin_fmaf(w1.z, xs[bb][6], pv);
        pv = __builtin_fmaf(w1.w, xs[bb][7], pv);
        if (MODE == 0) s_r[bb][pp] += pv;
        else           pr[bb][pp] = pv;
      }
    }

    // pass 2 (MODE!=0): v-dot, in-wave DPP softmax, accumulate
    if (MODE != 0) {
      float4 va[4], vc[4];
      #pragma unroll
      for (int bb = 0; bb < 4; ++bb) {
        const float4* vp =
            (const float4*)(v_in + (size_t)(b0w + bb) * OP_ + lane * 8);
        va[bb] = vp[0];
        vc[bb] = vp[1];
      }
      #pragma unroll
      for (int bb = 0; bb < 4; ++bb) {
        float acc = pr[bb][0] * va[bb].x;
        acc = __builtin_fmaf(pr[bb][1], va[bb].y, acc);
        acc = __builtin_fmaf(pr[bb][2], va[bb].z, acc);
        acc = __builtin_fmaf(pr[bb][3], va[bb].w, acc);
        acc = __builtin_fmaf(pr[bb][4], vc[bb].x, acc);
        acc = __builtin_fmaf(pr[bb][5], vc[bb].y, acc);
        acc = __builtin_fmaf(pr[bb][6], vc[bb].z, acc);
        acc = __builtin_fmaf(pr[bb][7], vc[bb].w, acc);
        // full logit = both p-halves (quad_perm xor1 pairs lanes 2o/2o+1)
        const float full = dpp_add<0xB1>(acc);
        const float e = __expf(full);
        // sum over all 64 lanes = 2*Z[b] (each o counted twice via ph)
        float srow = e;
        srow = dpp_add<0x121>(srow);
        srow = dpp_add<0x122>(srow);
        srow = dpp_add<0x124>(srow);
        srow = dpp_add<0x128>(srow);
        float t16 = srow + __shfl_xor(srow, 16);
        const float S = t16 + __shfl_xor(t16, 32);   // = 2*Z
        const float rw = (2.0f * e) / S;             // e/Z
        #pragma unroll
        for (int pp = 0; pp < 8; ++pp)
          s_r[bb][pp] = __builtin_fmaf(rw, pr[bb][pp], s_r[bb][pp]);
        if (MODE == 2) {
          if (ph == 0)
            rw_out[((size_t)(b0w + bb) * N_ + n) * O_ + o] = rw;
        }
      }
    }

    // publish W[n+1] into the other buffer; single barrier per nn.
    if (nn + 1 < CHUNK_) {
      *(float4*)&wnxt[swk]        = wr0;  // compiler inserts vmcnt wait
      *(float4*)&wnxt[swk + 1024] = wr1;
      *(float4*)&wnxt[swk + 2048] = wr2;
      *(float4*)&wnxt[swk + 3072] = wr3;
      __syncthreads();
    }
  }

  // epilogue, spart layout [cn][b][h][lane][4]: each float4 store is
  // base + lane*16B -> contiguous 1KB per instr.
  if (ATOMIC) {
    #pragma unroll
    for (int bb = 0; bb < 4; ++bb) {
      #pragma unroll
      for (int h = 0; h < 2; ++h)
        #pragma unroll
        for (int j = 0; j < 4; ++j)
          atomicAdd(&s_out[(size_t)(b0w + bb) * 512 + h * 256 + lane * 4 + j],
                    s_r[bb][h * 4 + j]);
    }
  } else {
    #pragma unroll
    for (int bb = 0; bb < 4; ++bb) {
      float* sp = s_out + (size_t)cn * M_ + (size_t)(b0w + bb) * 512 + lane * 4;
      float4 st0, st1;
      st0.x = s_r[bb][0]; st0.y = s_r[bb][1]; st0.z = s_r[bb][2]; st0.w = s_r[bb][3];
      st1.x = s_r[bb][4]; st1.y = s_r[bb][5]; st1.z = s_r[bb][6]; st1.w = s_r[bb][7];
      *(float4*)sp = st0;
      *(float4*)(sp + 256) = st1;
    }
  }
}

// stage-1 reduction: P[K][M_] -> P2[16][M_]; grid 16 groups x 16 m-chunks.
// (element-wise over flat M_, layout-agnostic)
__global__ __launch_bounds__(1024)
void reduce1(const float* __restrict__ spart, float* __restrict__ p2, int K) {
  const int g  = blockIdx.x >> 4;
  const int mc = blockIdx.x & 15;
  const int kpg = K >> 4;
  const int m0 = mc * 2048 + threadIdx.x;
  float a0 = 0.0f, a1 = 0.0f;
  const float* p = spart + (size_t)(g * kpg) * M_;
  for (int k = 0; k < kpg; ++k) {
    a0 += p[(size_t)k * M_ + m0];
    a1 += p[(size_t)k * M_ + m0 + 1024];
  }
  p2[(size_t)g * M_ + m0]        = a0;
  p2[(size_t)g * M_ + m0 + 1024] = a1;
}

// sum ngroups (stride M_) + squash; optional v_add / zero_buf.
// src group layout from fused_pass: idx(b,o,p) = b*512 + ((p>>2)&1)*256 +
// (2*o + (p>>3))*4 + (p&3).
__global__ __launch_bounds__(1024)
void v_kernel(const float* __restrict__ src, int ngroups, float scale,
              const float* __restrict__ v_add, float* __restrict__ v_out,
              float* __restrict__ zero_buf) {
  __shared__ float sq[P_ * 65];
  const int t = threadIdx.x;
  const int p = t & 15;
  const int b = t >> 4;
  const int o = blockIdx.x;
  const int q = o * P_ + p;
  const int idx_src = b * 512 + ((p >> 2) & 1) * 256 + (2 * o + (p >> 3)) * 4 +
                      (p & 3);
  float acc = 0.0f;
  for (int g = 0; g < ngroups; ++g)
    acc += src[(size_t)g * M_ + idx_src];
  acc *= scale;
  sq[p * 65 + b] = acc * acc;
  if (zero_buf) zero_buf[blockIdx.x * 1024 + t] = 0.0f;
  __syncthreads();
  float s2 = 0.0f;
  #pragma unroll
  for (int pp = 0; pp < P_; ++pp) s2 += sq[pp * 65 + b];
  float sc = (s2 / (1.0f + s2)) / sqrtf(s2 + 1e-7f);
  float v = acc * sc;
  const int idx = b * OP_ + q;   // v layout [b][o][p]
  v_out[idx] = v + (v_add ? v_add[idx] : 0.0f);
}

extern "C" void kernel_launch(void* const* d_in, const int* in_sizes, int n_in,
                              void* d_out, int out_size, void* d_ws, size_t ws_size,
                              hipStream_t stream) {
  (void)in_sizes; (void)n_in; (void)out_size;
  const float* x = (const float*)d_in[0];
  const float* W = (const float*)d_in[1];
  float* out_v  = (float*)d_out;                       // [64][32][16]
  float* out_rw = out_v + (size_t)B_ * O_ * P_;        // [64][2048][32]
  float* vws   = (float*)d_ws;                         // v0
  float* vsum  = vws + M_;                             // v0+v1
  float* p2    = vsum + M_;                            // 16 * M_
  float* spart = p2 + 16 * M_;                         // NBLK_ * M_

  const size_t need = (size_t)(2 * M_ + 16 * M_ + (size_t)NBLK_ * M_) * 4;

  dim3 gF(4 * NBLK_), bF(256), gV(O_), bV(1024), gR(256), bR(1024);
  if (ws_size >= need) {
    fused_pass<0, false><<<gF, bF, 0, stream>>>(x, W, nullptr, spart, nullptr);
    reduce1<<<gR, bR, 0, stream>>>(spart, p2, NBLK_);
    v_kernel<<<gV, bV, 0, stream>>>(p2, 16, 1.0f / 32.0f, nullptr, vws, nullptr);
    fused_pass<1, false><<<gF, bF, 0, stream>>>(x, W, vws, spart, nullptr);
    reduce1<<<gR, bR, 0, stream>>>(spart, p2, NBLK_);
    v_kernel<<<gV, bV, 0, stream>>>(p2, 16, 1.0f, vws, vsum, nullptr);
    fused_pass<2, false><<<gF, bF, 0, stream>>>(x, W, vsum, spart, out_rw);
    reduce1<<<gR, bR, 0, stream>>>(spart, p2, NBLK_);
    v_kernel<<<gV, bV, 0, stream>>>(p2, 16, 1.0f, nullptr, out_v, nullptr);
  } else {
    // atomic fallback for small ws
    float* sAb = p2;
    float* sBb = sAb + M_;
    hipMemsetAsync(sAb, 0, (size_t)M_ * sizeof(float), stream);
    fused_pass<0, true><<<gF, bF, 0, stream>>>(x, W, nullptr, sAb, nullptr);
    v_kernel<<<gV, bV, 0, stream>>>(sAb, 1, 1.0f / 32.0f, nullptr, vws, sBb);
    fused_pass<1, true><<<gF, bF, 0, stream>>>(x, W, vws, sBb, nullptr);
    v_kernel<<<gV, bV, 0, stream>>>(sBb, 1, 1.0f, vws, vsum, sAb);
    fused_pass<2, true><<<gF, bF, 0, stream>>>(x, W, vsum, sAb, out_rw);
    v_kernel<<<gV, bV, 0, stream>>>(sAb, 1, 1.0f, nullptr, out_v, nullptr);
  }
}